// Round 1
// baseline (1411.125 us; speedup 1.0000x reference)
//
#include <hip/hip_runtime.h>
#include <math.h>

// Problem constants (B=1)
#define NH    12      // heads
#define NRES  768     // sequence length
#define C1V   384
#define C2V   128
#define NPROJ 1152    // 192+192+192+144+144+288
#define QKD   28      // 16 scalar + 12 point dims
#define FDIM  2112    // 192 + 3*96 + 96 + 1536

__device__ __forceinline__ float softplusf_(float x) {
    return (x > 20.f) ? x : log1pf(__expf(x));
}
__device__ __forceinline__ float dot4(float4 a, float4 b) {
    return a.x*b.x + a.y*b.y + a.z*b.z + a.w*b.w;
}

// ---------------------------------------------------------------------------
// K1: proj = act @ [wq|wk|wv|wqp|wkp|wvp] + [0|0|0|bqp|bkp|bvp]
//     M=768, N=1152, K=384. 64x64 tiles, 4x4 micro, 256 threads.
// ---------------------------------------------------------------------------
__global__ __launch_bounds__(256) void k1_proj(
    const float* __restrict__ act,
    const float* __restrict__ wq, const float* __restrict__ wk,
    const float* __restrict__ wv, const float* __restrict__ wqp,
    const float* __restrict__ wkp, const float* __restrict__ wvp,
    const float* __restrict__ bqp, const float* __restrict__ bkp,
    const float* __restrict__ bvp, float* __restrict__ proj)
{
    __shared__ float As[64 * 33];
    __shared__ float Bs[32 * 65];
    const int n0 = blockIdx.x * 64, m0 = blockIdx.y * 64;
    const int tid = threadIdx.x;
    const int tx = tid & 15, ty = tid >> 4;
    float c[4][4] = {};

    for (int kt = 0; kt < C1V; kt += 32) {
        for (int idx = tid; idx < 64 * 32; idx += 256) {
            int r = idx >> 5, j = idx & 31;
            As[r * 33 + j] = act[(m0 + r) * C1V + kt + j];
        }
        for (int idx = tid; idx < 32 * 64; idx += 256) {
            int r = idx >> 6, col = idx & 63;
            int jj = n0 + col, k = kt + r;
            float w;
            if      (jj < 192) w = wq [k * 192 + jj];
            else if (jj < 384) w = wk [k * 192 + jj - 192];
            else if (jj < 576) w = wv [k * 192 + jj - 384];
            else if (jj < 720) w = wqp[k * 144 + jj - 576];
            else if (jj < 864) w = wkp[k * 144 + jj - 720];
            else               w = wvp[k * 288 + jj - 864];
            Bs[r * 65 + col] = w;
        }
        __syncthreads();
        #pragma unroll
        for (int kk = 0; kk < 32; ++kk) {
            float a[4], b[4];
            #pragma unroll
            for (int i = 0; i < 4; ++i) a[i] = As[(ty * 4 + i) * 33 + kk];
            #pragma unroll
            for (int j = 0; j < 4; ++j) b[j] = Bs[kk * 65 + tx * 4 + j];
            #pragma unroll
            for (int i = 0; i < 4; ++i)
                #pragma unroll
                for (int j = 0; j < 4; ++j) c[i][j] += a[i] * b[j];
        }
        __syncthreads();
    }
    float biasv[4];
    #pragma unroll
    for (int j = 0; j < 4; ++j) {
        int col = n0 + tx * 4 + j;
        biasv[j] = (col >= 864) ? bvp[col - 864]
                 : (col >= 720) ? bkp[col - 720]
                 : (col >= 576) ? bqp[col - 576] : 0.f;
    }
    #pragma unroll
    for (int i = 0; i < 4; ++i) {
        float4 v;
        v.x = c[i][0] + biasv[0]; v.y = c[i][1] + biasv[1];
        v.z = c[i][2] + biasv[2]; v.w = c[i][3] + biasv[3];
        *(float4*)&proj[(m0 + ty * 4 + i) * NPROJ + n0 + tx * 4] = v;
    }
}

// ---------------------------------------------------------------------------
// K2: per-residue prep. Builds Qv[n][h][28] (q*0.25 | pw*qp_global),
//     Kv[n][h][28] (k | kp_global), ak[n][h] = -0.5*pw*sum|kp|^2,
//     vpArr[n][h*24+p*3+d] = global-frame value points.
//     proj layout: q 0..191 | k 192..383 | v 384..575 | qp 576..719
//                  | kp 720..863 | vp 864..1151.  point col = h*3P + d*P + p.
// ---------------------------------------------------------------------------
__global__ __launch_bounds__(64) void k2_prep(
    const float* __restrict__ proj, const float* __restrict__ rot,
    const float* __restrict__ trans, const float* __restrict__ tw,
    float* __restrict__ Qv, float* __restrict__ Kv,
    float* __restrict__ akArr, float* __restrict__ vpArr)
{
    const int n = blockIdx.x, tid = threadIdx.x;
    __shared__ float kp2[48];
    const float* pr = proj + n * NPROJ;
    float R[9], T[3];
    #pragma unroll
    for (int i = 0; i < 9; ++i) R[i] = rot[n * 9 + i];
    #pragma unroll
    for (int i = 0; i < 3; ++i) T[i] = trans[n * 3 + i];

    for (int idx = tid; idx < 192; idx += 64) {
        int h = idx >> 4, cc = idx & 15;
        Qv[(n * NH + h) * QKD + cc] = pr[idx] * 0.25f;          // sqrt(1/16)
        Kv[(n * NH + h) * QKD + cc] = pr[192 + idx];
    }
    if (tid < 48) {
        int h = tid >> 2, p = tid & 3;
        float pwh = 0.23570226039551584f * softplusf_(tw[h]);   // sqrt(2/36)*softplus
        // qp
        float lx = pr[576 + h * 12 + p];
        float ly = pr[576 + h * 12 + 4 + p];
        float lz = pr[576 + h * 12 + 8 + p];
        float gx = R[0] * lx + R[1] * ly + R[2] * lz + T[0];
        float gy = R[3] * lx + R[4] * ly + R[5] * lz + T[1];
        float gz = R[6] * lx + R[7] * ly + R[8] * lz + T[2];
        float* qd = &Qv[(n * NH + h) * QKD + 16];
        qd[p] = pwh * gx; qd[4 + p] = pwh * gy; qd[8 + p] = pwh * gz;
        // kp
        lx = pr[720 + h * 12 + p];
        ly = pr[720 + h * 12 + 4 + p];
        lz = pr[720 + h * 12 + 8 + p];
        gx = R[0] * lx + R[1] * ly + R[2] * lz + T[0];
        gy = R[3] * lx + R[4] * ly + R[5] * lz + T[1];
        gz = R[6] * lx + R[7] * ly + R[8] * lz + T[2];
        float* kd = &Kv[(n * NH + h) * QKD + 16];
        kd[p] = gx; kd[4 + p] = gy; kd[8 + p] = gz;
        kp2[tid] = gx * gx + gy * gy + gz * gz;
    }
    __syncthreads();
    if (tid < NH) {
        float pwh = 0.23570226039551584f * softplusf_(tw[tid]);
        akArr[n * NH + tid] = -0.5f * pwh *
            (kp2[tid * 4] + kp2[tid * 4 + 1] + kp2[tid * 4 + 2] + kp2[tid * 4 + 3]);
    }
    for (int idx = tid; idx < 96; idx += 64) {
        int h = idx >> 3, p = idx & 7;
        float lx = pr[864 + h * 24 + p];
        float ly = pr[864 + h * 24 + 8 + p];
        float lz = pr[864 + h * 24 + 16 + p];
        float gx = R[0] * lx + R[1] * ly + R[2] * lz + T[0];
        float gy = R[3] * lx + R[4] * ly + R[5] * lz + T[1];
        float gz = R[6] * lx + R[7] * ly + R[8] * lz + T[2];
        float* dst = &vpArr[n * 288 + h * 24 + p * 3];
        dst[0] = gx; dst[1] = gy; dst[2] = gz;
    }
}

// ---------------------------------------------------------------------------
// K2b: qkBuf[q][h][k] = Qv[q,h,:] . Kv[k,h,:] + ak[k,h]   (28-deep dot)
//      grid (ktile, qtile, h); 64x64 tile, 4x4 micro.
// ---------------------------------------------------------------------------
__global__ __launch_bounds__(256) void k2b_qk(
    const float* __restrict__ Qv, const float* __restrict__ Kv,
    const float* __restrict__ akArr, float* __restrict__ qkBuf)
{
    const int h = blockIdx.z;
    const int k0 = blockIdx.x * 64, q0 = blockIdx.y * 64;
    __shared__ float As[64 * 29];
    __shared__ float Bs[64 * 29];
    const int tid = threadIdx.x, tx = tid & 15, ty = tid >> 4;

    for (int idx = tid; idx < 64 * 28; idx += 256) {
        int r = idx / 28, j = idx - r * 28;
        As[r * 29 + j] = Qv[((q0 + r) * NH + h) * QKD + j];
        Bs[r * 29 + j] = Kv[((k0 + r) * NH + h) * QKD + j];
    }
    __syncthreads();
    float c[4][4] = {};
    #pragma unroll
    for (int kk = 0; kk < 28; ++kk) {
        float a[4], b[4];
        #pragma unroll
        for (int i = 0; i < 4; ++i) a[i] = As[(ty * 4 + i) * 29 + kk];
        #pragma unroll
        for (int j = 0; j < 4; ++j) b[j] = Bs[(tx * 4 + j) * 29 + kk];
        #pragma unroll
        for (int i = 0; i < 4; ++i)
            #pragma unroll
            for (int j = 0; j < 4; ++j) c[i][j] += a[i] * b[j];
    }
    float akv[4];
    #pragma unroll
    for (int j = 0; j < 4; ++j) akv[j] = akArr[(k0 + tx * 4 + j) * NH + h];
    #pragma unroll
    for (int i = 0; i < 4; ++i) {
        float4 v;
        v.x = c[i][0] + akv[0]; v.y = c[i][1] + akv[1];
        v.z = c[i][2] + akv[2]; v.w = c[i][3] + akv[3];
        *(float4*)&qkBuf[((q0 + ty * 4 + i) * NH + h) * NRES + k0 + tx * 4] = v;
    }
}

// ---------------------------------------------------------------------------
// K3: fused attention per query q (one block, 256 threads).
//   Phase A: logits[k,h] = qkBuf + act2d.w2d (b2d/aq cancel in softmax),
//            mask, *sqrt(1/3).  Softmax over k in LDS (unnormalized exp + 1/l).
//   Phase B: r2d / res_scalar / rpg accumulations; rpl = R^T(rpg - t); norms.
//   Writes F[q][2112] = [res(192) | rpl_x(96) | rpl_y | rpl_z | norms | r2d(1536)]
// ---------------------------------------------------------------------------
__global__ __launch_bounds__(256, 3) void k3_attn(
    const float* __restrict__ act2d, const float* __restrict__ smask,
    const float* __restrict__ w2d, const float* __restrict__ rot,
    const float* __restrict__ trans, const float* __restrict__ proj,
    const float* __restrict__ qkBuf, const float* __restrict__ vpArr,
    float* __restrict__ F)
{
    const int q = blockIdx.x, tid = threadIdx.x;
    __shared__ __align__(16) float w2dT[NH * 128];   // [h][c]
    __shared__ float attnS[NH * NRES];               // [h][k], 36 KB
    __shared__ float red[NH * 4];
    __shared__ float mh[NH], lh[NH];
    __shared__ float rpgS[288];
    __shared__ float rotS[9], transS[3];

    for (int idx = tid; idx < C2V * NH; idx += 256)
        w2dT[(idx % NH) * 128 + (idx / NH)] = w2d[idx];
    if (tid < 9) rotS[tid] = rot[q * 9 + tid];
    if (tid < 3) transS[tid] = trans[q * 3 + tid];
    __syncthreads();

    const float smq = smask[q];
    const float scale = 0.5773502691896258f;   // sqrt(1/3)

    // ---- Phase A: this thread owns k = tid, tid+256, tid+512 ----
    float lg[3][NH];
    #pragma unroll
    for (int h = 0; h < NH; ++h)
        #pragma unroll
        for (int i = 0; i < 3; ++i)
            lg[i][h] = qkBuf[(q * NH + h) * NRES + tid + 256 * i];

    const float* arow = act2d + ((size_t)q * NRES + tid) * C2V;
    for (int cb = 0; cb < 128; cb += 8) {
        float4 av[3][2];
        #pragma unroll
        for (int i = 0; i < 3; ++i) {
            const float* p = arow + (size_t)i * 256 * C2V + cb;
            av[i][0] = *(const float4*)p;
            av[i][1] = *(const float4*)(p + 4);
        }
        #pragma unroll
        for (int h = 0; h < NH; ++h) {
            float4 w0 = *(const float4*)&w2dT[h * 128 + cb];
            float4 w1 = *(const float4*)&w2dT[h * 128 + cb + 4];
            #pragma unroll
            for (int i = 0; i < 3; ++i)
                lg[i][h] += dot4(av[i][0], w0) + dot4(av[i][1], w1);
        }
    }
    #pragma unroll
    for (int i = 0; i < 3; ++i) {
        float smk = smask[tid + 256 * i];
        float msk = -1e5f * (1.f - smq * smk);
        #pragma unroll
        for (int h = 0; h < NH; ++h) lg[i][h] = (lg[i][h] + msk) * scale;
    }

    // ---- softmax over k ----
    const int wv_ = tid >> 6, lane = tid & 63;
    #pragma unroll
    for (int h = 0; h < NH; ++h) {
        float v = fmaxf(fmaxf(lg[0][h], lg[1][h]), lg[2][h]);
        for (int off = 32; off > 0; off >>= 1) v = fmaxf(v, __shfl_down(v, off, 64));
        if (lane == 0) red[h * 4 + wv_] = v;
    }
    __syncthreads();
    if (tid < NH)
        mh[tid] = fmaxf(fmaxf(red[tid * 4], red[tid * 4 + 1]),
                        fmaxf(red[tid * 4 + 2], red[tid * 4 + 3]));
    __syncthreads();
    float lsum[NH];
    #pragma unroll
    for (int h = 0; h < NH; ++h) lsum[h] = 0.f;
    #pragma unroll
    for (int i = 0; i < 3; ++i)
        #pragma unroll
        for (int h = 0; h < NH; ++h) {
            float e = __expf(lg[i][h] - mh[h]);
            attnS[h * NRES + tid + 256 * i] = e;
            lsum[h] += e;
        }
    #pragma unroll
    for (int h = 0; h < NH; ++h) {
        float v = lsum[h];
        for (int off = 32; off > 0; off >>= 1) v += __shfl_down(v, off, 64);
        if (lane == 0) red[h * 4 + wv_] = v;
    }
    __syncthreads();
    if (tid < NH)
        lh[tid] = 1.f / (red[tid * 4] + red[tid * 4 + 1] + red[tid * 4 + 2] + red[tid * 4 + 3]);
    __syncthreads();

    // ---- Phase B ----
    const float* a2b = act2d + (size_t)q * NRES * C2V;
    const int h0 = tid >> 5,          c0 = (tid & 31) << 2;            // r2d slot tid
    const int h1 = (256 + tid) >> 5,  c1 = ((256 + tid) & 31) << 2;    // r2d slot 256+tid (tid<128)
    const int hr = tid >> 4;                                           // res slot (tid<192)
    const int hv0 = tid / 24;                                          // rpg slot tid
    const int hv1 = (256 + tid) / 24;                                  // rpg slot 256+tid (tid<32)
    const float* at0 = attnS + h0 * NRES;
    const float* at1 = attnS + h1 * NRES;
    const float* atr = attnS + hr * NRES;
    const float* apv0 = attnS + hv0 * NRES;
    const float* apv1 = attnS + hv1 * NRES;
    float4 acc0 = {0, 0, 0, 0}, acc1 = {0, 0, 0, 0};
    float accRes = 0.f, accP0 = 0.f, accP1 = 0.f;

    #pragma unroll 4
    for (int k = 0; k < NRES; ++k) {
        const float* rk = a2b + (size_t)k * C2V;
        float4 a = *(const float4*)(rk + c0);
        float p0 = at0[k];
        acc0.x += p0 * a.x; acc0.y += p0 * a.y; acc0.z += p0 * a.z; acc0.w += p0 * a.w;
        if (tid < 128) {
            float4 b = *(const float4*)(rk + c1);
            float p1 = at1[k];
            acc1.x += p1 * b.x; acc1.y += p1 * b.y; acc1.z += p1 * b.z; acc1.w += p1 * b.w;
        }
        if (tid < 192) accRes += atr[k] * proj[k * NPROJ + 384 + tid];
        accP0 += apv0[k] * vpArr[k * 288 + tid];
        if (tid < 32) accP1 += apv1[k] * vpArr[k * 288 + 256 + tid];
    }

    float* Fq = F + q * FDIM;
    {
        float il = lh[h0];
        float4 v = {acc0.x * il, acc0.y * il, acc0.z * il, acc0.w * il};
        *(float4*)(Fq + 576 + tid * 4) = v;
    }
    if (tid < 128) {
        float il = lh[h1];
        float4 v = {acc1.x * il, acc1.y * il, acc1.z * il, acc1.w * il};
        *(float4*)(Fq + 576 + (256 + tid) * 4) = v;
    }
    if (tid < 192) Fq[tid] = accRes * lh[hr];
    rpgS[tid] = accP0 * lh[hv0];
    if (tid < 32) rpgS[256 + tid] = accP1 * lh[hv1];
    __syncthreads();
    if (tid < 96) {
        float gx = rpgS[tid * 3]     - transS[0];
        float gy = rpgS[tid * 3 + 1] - transS[1];
        float gz = rpgS[tid * 3 + 2] - transS[2];
        // invert_apply: rpl_i = sum_j R[j][i] * g_j
        float x = rotS[0] * gx + rotS[3] * gy + rotS[6] * gz;
        float y = rotS[1] * gx + rotS[4] * gy + rotS[7] * gz;
        float z = rotS[2] * gx + rotS[5] * gy + rotS[8] * gz;
        Fq[192 + tid] = x;
        Fq[288 + tid] = y;
        Fq[384 + tid] = z;
        Fq[480 + tid] = sqrtf(x * x + y * y + z * z);
    }
}

// ---------------------------------------------------------------------------
// K5: out = F @ wfin + bfin.  M=768, N=384, K=2112, split-K x3 via atomics.
// ---------------------------------------------------------------------------
__global__ __launch_bounds__(256) void k5_final(
    const float* __restrict__ F, const float* __restrict__ wfin,
    const float* __restrict__ bfin, float* __restrict__ out)
{
    const int n0 = blockIdx.x * 64, m0 = blockIdx.y * 64, kz = blockIdx.z;
    const int kbeg = kz * 704;
    __shared__ float As[64 * 33];
    __shared__ float Bs[32 * 65];
    const int tid = threadIdx.x, tx = tid & 15, ty = tid >> 4;
    float c[4][4] = {};

    for (int kt = kbeg; kt < kbeg + 704; kt += 32) {
        for (int idx = tid; idx < 64 * 32; idx += 256) {
            int r = idx >> 5, j = idx & 31;
            As[r * 33 + j] = F[(m0 + r) * FDIM + kt + j];
        }
        for (int idx = tid; idx < 32 * 64; idx += 256) {
            int r = idx >> 6, col = idx & 63;
            Bs[r * 65 + col] = wfin[(kt + r) * 384 + n0 + col];
        }
        __syncthreads();
        #pragma unroll
        for (int kk = 0; kk < 32; ++kk) {
            float a[4], b[4];
            #pragma unroll
            for (int i = 0; i < 4; ++i) a[i] = As[(ty * 4 + i) * 33 + kk];
            #pragma unroll
            for (int j = 0; j < 4; ++j) b[j] = Bs[kk * 65 + tx * 4 + j];
            #pragma unroll
            for (int i = 0; i < 4; ++i)
                #pragma unroll
                for (int j = 0; j < 4; ++j) c[i][j] += a[i] * b[j];
        }
        __syncthreads();
    }
    #pragma unroll
    for (int i = 0; i < 4; ++i)
        #pragma unroll
        for (int j = 0; j < 4; ++j) {
            float v = c[i][j];
            if (kz == 0) v += bfin[n0 + tx * 4 + j];
            atomicAdd(&out[(m0 + ty * 4 + i) * 384 + n0 + tx * 4 + j], v);
        }
}

// ---------------------------------------------------------------------------
extern "C" void kernel_launch(void* const* d_in, const int* in_sizes, int n_in,
                              void* d_out, int out_size, void* d_ws, size_t ws_size,
                              hipStream_t stream) {
    const float* act   = (const float*)d_in[0];
    const float* act2d = (const float*)d_in[1];
    const float* smask = (const float*)d_in[2];
    const float* rot   = (const float*)d_in[3];
    const float* trans = (const float*)d_in[4];
    const float* wq    = (const float*)d_in[5];
    const float* wk    = (const float*)d_in[6];
    const float* wvv   = (const float*)d_in[7];
    const float* wqp   = (const float*)d_in[8];
    const float* bqp   = (const float*)d_in[9];
    const float* wkp   = (const float*)d_in[10];
    const float* bkp   = (const float*)d_in[11];
    const float* wvp   = (const float*)d_in[12];
    const float* bvp   = (const float*)d_in[13];
    const float* w2d   = (const float*)d_in[14];
    // d_in[15] = b2d: constant over k, cancels in softmax over k -> unused
    const float* wfin  = (const float*)d_in[16];
    const float* bfin  = (const float*)d_in[17];
    const float* tw    = (const float*)d_in[18];

    // workspace layout (floats); total 10,331,136 floats = 41.3 MB
    float* W     = (float*)d_ws;
    float* proj  = W;                      // 768*1152
    float* Qv    = proj  + 768 * NPROJ;    // 768*12*28
    float* Kv    = Qv    + 768 * NH * QKD;
    float* akArr = Kv    + 768 * NH * QKD; // 768*12
    float* vpArr = akArr + 768 * NH;       // 768*288
    float* qkBuf = vpArr + 768 * 288;      // 768*12*768
    float* F     = qkBuf + 768 * NH * NRES;// 768*2112

    k1_proj<<<dim3(18, 12), 256, 0, stream>>>(act, wq, wk, wvv, wqp, wkp, wvp,
                                              bqp, bkp, bvp, proj);
    k2_prep<<<dim3(NRES), 64, 0, stream>>>(proj, rot, trans, tw, Qv, Kv, akArr, vpArr);
    k2b_qk<<<dim3(12, 12, NH), 256, 0, stream>>>(Qv, Kv, akArr, qkBuf);
    k3_attn<<<dim3(NRES), 256, 0, stream>>>(act2d, smask, w2d, rot, trans, proj,
                                            qkBuf, vpArr, F);
    hipMemsetAsync(d_out, 0, (size_t)out_size * sizeof(float), stream);
    k5_final<<<dim3(6, 12, 3), 256, 0, stream>>>(F, wfin, bfin, (float*)d_out);
}